// Round 11
// baseline (842.848 us; speedup 1.0000x reference)
//
#include <hip/hip_runtime.h>
#include <hip/hip_bf16.h>

typedef short bf16x8 __attribute__((ext_vector_type(8)));
typedef float f32x4 __attribute__((ext_vector_type(4)));
typedef unsigned short u16;

__device__ __forceinline__ float bf2f(u16 u) {
    union { unsigned int i; float f; } x; x.i = ((unsigned int)u) << 16; return x.f;
}
__device__ __forceinline__ u16 f2bf(float f) {
    union { float f; unsigned int i; } x; x.f = f;
    unsigned int r = x.i + 0x7fff + ((x.i >> 16) & 1);
    return (u16)(r >> 16);
}
__device__ __forceinline__ f32x4 mfma16(bf16x8 a, bf16x8 b, f32x4 c) {
    return __builtin_amdgcn_mfma_f32_16x16x32_bf16(a, b, c, 0, 0, 0);
}
#define GLL16(lds_base, gsrc) \
    __builtin_amdgcn_global_load_lds((const __attribute__((address_space(1))) void*)(gsrc), \
                                     (__attribute__((address_space(3))) void*)(lds_base), 16, 0, 0)

// ------------- transpose fp32 [R][C] -> bf16 [C][R] ---------------------
__global__ __launch_bounds__(256)
void transpose_kernel(const float* __restrict__ in, u16* __restrict__ out, int R, int C) {
    __shared__ float t[32][33];
    const int c0 = blockIdx.x * 32, r0 = blockIdx.y * 32;
    const int tx = threadIdx.x & 31, ty = threadIdx.x >> 5; // ty 0..7
#pragma unroll
    for (int i = 0; i < 32; i += 8) t[ty + i][tx] = in[(size_t)(r0 + ty + i) * C + c0 + tx];
    __syncthreads();
#pragma unroll
    for (int i = 0; i < 32; i += 8) out[(size_t)(c0 + ty + i) * R + r0 + tx] = f2bf(t[tx][ty + i]);
}

// ------------- fp32 -> bf16 convert (8 elems/thread) --------------------
__global__ __launch_bounds__(256)
void convert_kernel(const float* __restrict__ in, u16* __restrict__ out) {
    const size_t i = ((size_t)blockIdx.x * 256 + threadIdx.x) * 8;
    const float4 a = *(const float4*)(in + i);
    const float4 b = *(const float4*)(in + i + 4);
    bf16x8 o;
    o[0] = (short)f2bf(a.x); o[1] = (short)f2bf(a.y);
    o[2] = (short)f2bf(a.z); o[3] = (short)f2bf(a.w);
    o[4] = (short)f2bf(b.x); o[5] = (short)f2bf(b.y);
    o[6] = (short)f2bf(b.z); o[7] = (short)f2bf(b.w);
    *(bf16x8*)(out + i) = o;
}

// ------------- positional embedding pe[2048][1024] (bf16) ---------------
__global__ __launch_bounds__(256)
void pe_kernel(u16* __restrict__ pe) {
    const int idx = blockIdx.x * 256 + threadIdx.x; // 2M elements
    const int p = idx >> 10, d = idx & 1023;
    const float pos = (float)(2047 - p);
    const int k = d & 511;
    const float invf = powf(10000.f, ((float)(2 * k)) * (-1.f / 1024.f));
    const float a = pos * invf;
    pe[idx] = f2bf((d < 512) ? sinf(a) : cosf(a));
}

// ------------- LayerNorm (fp32 in, bf16 out), one wave per row ----------
__global__ __launch_bounds__(256)
void ln_kernel(const float* __restrict__ inp, const float* __restrict__ gg,
               const float* __restrict__ bb, u16* __restrict__ outp) {
    const int row = blockIdx.x * 4 + (threadIdx.x >> 6);
    const int l = threadIdx.x & 63;
    const size_t base = (size_t)row * 1024 + l * 16;
    float v[16];
    const float4* p4 = (const float4*)(inp + base);
#pragma unroll
    for (int j = 0; j < 4; ++j) {
        float4 f = p4[j];
        v[j*4+0] = f.x; v[j*4+1] = f.y; v[j*4+2] = f.z; v[j*4+3] = f.w;
    }
    float s = 0.f, s2 = 0.f;
#pragma unroll
    for (int j = 0; j < 16; ++j) { s += v[j]; s2 += v[j] * v[j]; }
#pragma unroll
    for (int off = 1; off < 64; off <<= 1) {
        s += __shfl_xor(s, off, 64);
        s2 += __shfl_xor(s2, off, 64);
    }
    const float mu = s * 0.0009765625f;
    const float var = s2 * 0.0009765625f - mu * mu;
    const float rs = rsqrtf(var + 1e-5f);
#pragma unroll
    for (int j = 0; j < 16; ++j)
        outp[base + j] = f2bf((v[j] - mu) * rs * gg[l * 16 + j] + bb[l * 16 + j]);
}

// ---------------- GEMM: C[M][N] = A[M][K] @ W[K][N], Wt = W^T [N][K] ----
// 128x128 tile, 4 waves (2x2), 16x16x32 bf16 MFMA, BK=32.
// Staging via global_load_lds width=16 (m97 pattern).
template<int EPI, bool CATA>
__global__ __launch_bounds__(256)
void gemm_kernel(const u16* __restrict__ A, const u16* __restrict__ A2,
                 const u16* __restrict__ Wt, void* __restrict__ outp,
                 u16* __restrict__ out2, const float* __restrict__ cb1,
                 const float* __restrict__ cb2, const float* __restrict__ residp,
                 int Mdim, int Ndim, int Kdim) {
    __shared__ __attribute__((aligned(16))) u16 As[128 * 32];
    __shared__ __attribute__((aligned(16))) u16 Bs[128 * 32];
    const int tid = threadIdx.x;
    const int w = tid >> 6, l = tid & 63;
    const int wr = w >> 1, wc = w & 1;
    const int m0 = blockIdx.x * 128, n0 = blockIdx.y * 128;
    f32x4 acc[4][4] = {};

    for (int k0 = 0; k0 < Kdim; k0 += 32) {
        __syncthreads();
#pragma unroll
        for (int p = 0; p < 2; ++p) {
            const int ebase = (p * 4 + w) * 512;      // wave-uniform LDS base (u16 idx)
            const int e = ebase + l * 8;              // this lane's element
            const int row = e >> 5, colk = e & 31;
            const u16* srcA;
            if (CATA) { // rows: [memb(1024) ; xn(1024)] per batch, K=1024
                const int rr = m0 + row;
                const int bb_ = rr >> 11, pos = rr & 2047;
                srcA = (pos < 1024 ? A + ((size_t)(bb_ * 1024 + pos)) * 1024
                                   : A2 + ((size_t)(bb_ * 1024 + pos - 1024)) * 1024)
                       + (k0 + colk);
            } else {
                srcA = A + (size_t)(m0 + row) * Kdim + (k0 + colk);
            }
            const u16* srcB = Wt + (size_t)(n0 + row) * Kdim + (k0 + colk);
            GLL16(&As[ebase], srcA);
            GLL16(&Bs[ebase], srcB);
        }
        __syncthreads();
        bf16x8 af[4], bfr[4];
#pragma unroll
        for (int mi = 0; mi < 4; ++mi)
            af[mi] = *(const bf16x8*)&As[(wr * 64 + mi * 16 + (l & 15)) * 32 + (l >> 4) * 8];
#pragma unroll
        for (int ni = 0; ni < 4; ++ni)
            bfr[ni] = *(const bf16x8*)&Bs[(wc * 64 + ni * 16 + (l & 15)) * 32 + (l >> 4) * 8];
#pragma unroll
        for (int mi = 0; mi < 4; ++mi)
#pragma unroll
            for (int ni = 0; ni < 4; ++ni)
                acc[mi][ni] = mfma16(af[mi], bfr[ni], acc[mi][ni]);
    }

#pragma unroll
    for (int mi = 0; mi < 4; ++mi)
#pragma unroll
        for (int ni = 0; ni < 4; ++ni)
#pragma unroll
            for (int rg = 0; rg < 4; ++rg) {
                const int row = m0 + wr * 64 + mi * 16 + (l >> 4) * 4 + rg;
                const int col = n0 + wc * 64 + ni * 16 + (l & 15);
                const size_t idx = (size_t)row * Ndim + col;
                const float v = acc[mi][ni][rg];
                if (EPI == 0) {
                    ((u16*)outp)[idx] = f2bf(v);
                } else if (EPI == 1) {
                    ((u16*)outp)[idx] = f2bf(v + cb1[col]);
                    out2[idx] = f2bf(v + cb2[col]);
                } else if (EPI == 2) {
                    ((float*)outp)[idx] = v + residp[idx];
                } else if (EPI == 3) {
                    const float t = v + cb1[col];
                    ((u16*)outp)[idx] = f2bf(0.5f * t * (1.f + erff(t * 0.70710678118654752f)));
                } else {
                    ((float*)outp)[idx] = v + cb1[col] + residp[idx]; // fp32 y
                }
            }
}

// ---------------- fused rel-attention (flash-style) ---------------------
// grid: 1024 blocks (XCD-swizzled), 256 threads (4 waves x 16 q-rows).
// R-band loads are UNCONDITIONAL (rbuf padded +/-80 rows): used extractions
// provably have in-range m; pad-row garbage only reaches discarded columns.
__global__ __launch_bounds__(256, 3)
void attn_kernel(const u16* __restrict__ qu, const u16* __restrict__ qv,
                 const u16* __restrict__ kcat, const u16* __restrict__ vcat,
                 const u16* __restrict__ rbuf, u16* __restrict__ outp) {
    constexpr int T = 1024, L = 2048, MM = 1024;
    __shared__ __attribute__((aligned(16))) u16 Vt[2][64][72]; // V^T tile, dbuf
    __shared__ __attribute__((aligned(16))) u16 Pl[4][16][72]; // per-wave P tile
    const int bid = blockIdx.x;
    const int g = (bid & 7) + 8 * (bid >> 7);   // head-group 0..63 (XCD swizzle)
    const int it = (bid >> 3) & 15;
    const int h = g & 15, b = g >> 4;
    const int i0 = it * 64;
    const int tid = threadIdx.x;
    const int w = tid >> 6, l = tid & 63;
    const int lg = l >> 4, ll = l & 15;
    const int iw0 = i0 + w * 16;

    bf16x8 quf[2], qvf[2];
    const int qc = h * 64 + lg * 8;
    {
        const size_t qrow = (size_t)(b * T + iw0 + ll);
        quf[0] = *(const bf16x8*)&qu[qrow * 1024 + qc];
        quf[1] = *(const bf16x8*)&qu[qrow * 1024 + qc + 32];
        qvf[0] = *(const bf16x8*)&qv[qrow * 1024 + qc];
        qvf[1] = *(const bf16x8*)&qv[qrow * 1024 + qc + 32];
    }
    const int r2 = iw0 + ll + 1;
    const size_t qrow2 = (size_t)(b * T + (r2 < T ? r2 : T - 1)); // wrap row (lazy)
    const u16* kb = kcat + (size_t)b * L * 1024 + h * 64;
    const u16* vb = vcat + (size_t)b * L * 1024 + h * 64;
    const u16* rb = rbuf + h * 64;

    f32x4 o_acc[4] = {};
    float m_run[4] = {-1e30f, -1e30f, -1e30f, -1e30f};
    float l_run[4] = {0.f, 0.f, 0.f, 0.f};
    const int vjq = tid & 15, vdg = tid >> 4;   // V-stage: row-quad, col-group

    for (int jt = 0; jt < 32; ++jt) {
        const int j0 = jt * 64;
        const int buf = jt & 1;
        { // stage V^T: 4x ushort4 loads, in-reg 4x4 transpose, 4x ushort4 writes
            const u16* srcv = vb + (size_t)(j0 + vjq * 4) * 1024 + vdg * 4;
            const ushort4 r0 = *(const ushort4*)(srcv);
            const ushort4 r1 = *(const ushort4*)(srcv + 1024);
            const ushort4 r2w = *(const ushort4*)(srcv + 2048);
            const ushort4 r3 = *(const ushort4*)(srcv + 3072);
            const ushort4 c0 = {r0.x, r1.x, r2w.x, r3.x};
            const ushort4 c1 = {r0.y, r1.y, r2w.y, r3.y};
            const ushort4 c2 = {r0.z, r1.z, r2w.z, r3.z};
            const ushort4 c3 = {r0.w, r1.w, r2w.w, r3.w};
            *(ushort4*)&Vt[buf][vdg * 4 + 0][vjq * 4] = c0;
            *(ushort4*)&Vt[buf][vdg * 4 + 1][vjq * 4] = c1;
            *(ushort4*)&Vt[buf][vdg * 4 + 2][vjq * 4] = c2;
            *(ushort4*)&Vt[buf][vdg * 4 + 3][vjq * 4] = c3;
        }
        __syncthreads();

        // content scores
        f32x4 sv[4];
        __builtin_amdgcn_s_setprio(1);
#pragma unroll
        for (int ns = 0; ns < 4; ++ns) {
            f32x4 a = {0.f, 0.f, 0.f, 0.f};
            const u16* kp = kb + (size_t)(j0 + ns * 16 + ll) * 1024 + lg * 8;
            a = mfma16(quf[0], *(const bf16x8*)kp, a);
            a = mfma16(quf[1], *(const bf16x8*)(kp + 32), a);
            sv[ns] = a;
        }
        __builtin_amdgcn_s_setprio(0);

        // main band (wave-uniform condition; unconditional per-lane loads)
        if (j0 <= MM + iw0 + 15) {
            const int m0 = j0 + T - iw0 - 16;   // in-band m always >= 0, <= 2126
            f32x4 gb[5];
#pragma unroll
            for (int cs = 0; cs < 5; ++cs) {
                const u16* rp = rb + (m0 + cs * 16 + ll) * 1024 + lg * 8;
                f32x4 a = {0.f, 0.f, 0.f, 0.f};
                a = mfma16(qvf[0], *(const bf16x8*)rp, a);
                a = mfma16(qvf[1], *(const bf16x8*)(rp + 32), a);
                gb[cs] = a;
            }
#pragma unroll
            for (int r = 0; r < 4; ++r) {
                const int i_loc = lg * 4 + r;
                const int ig = iw0 + i_loc;
#pragma unroll
                for (int ns = 0; ns < 4; ++ns) {
                    const int j_loc = ns * 16 + ll;
                    const int c = j_loc + 15 - i_loc;
                    const int srcl = (l & 48) | (c & 15);
                    const float t0 = __shfl(gb[ns][r], srcl, 64);
                    const float t1 = __shfl(gb[ns + 1][r], srcl, 64);
                    const float gm = ((c >> 4) == ns) ? t0 : t1;
                    if (j0 + j_loc <= MM + ig) sv[ns][r] += gm;
                }
            }
        }
        // wrap band (wave-uniform condition; m in [-78, 1022] when active)
        if (j0 + 63 >= MM + iw0 + 2) {
            const bf16x8 qv2f0 = *(const bf16x8*)&qv[qrow2 * 1024 + qc];
            const bf16x8 qv2f1 = *(const bf16x8*)&qv[qrow2 * 1024 + qc + 32];
            const int m0w = j0 - MM - iw0 - 17;
            f32x4 gb[5];
#pragma unroll
            for (int cs = 0; cs < 5; ++cs) {
                const u16* rp = rb + (m0w + cs * 16 + ll) * 1024 + lg * 8;
                f32x4 a = {0.f, 0.f, 0.f, 0.f};
                a = mfma16(qv2f0, *(const bf16x8*)rp, a);
                a = mfma16(qv2f1, *(const bf16x8*)(rp + 32), a);
                gb[cs] = a;
            }
#pragma unroll
            for (int r = 0; r < 4; ++r) {
                const int i_loc = lg * 4 + r;
                const int ig = iw0 + i_loc;
#pragma unroll
                for (int ns = 0; ns < 4; ++ns) {
                    const int j_loc = ns * 16 + ll;
                    const int c = j_loc + 15 - i_loc;
                    const int srcl = (l & 48) | (c & 15);
                    const float t0 = __shfl(gb[ns][r], srcl, 64);
                    const float t1 = __shfl(gb[ns + 1][r], srcl, 64);
                    const float gw = ((c >> 4) == ns) ? t0 : t1;
                    if (j0 + j_loc >= MM + ig + 2) sv[ns][r] += gw;
                }
            }
        }

        // online softmax + write P
#pragma unroll
        for (int r = 0; r < 4; ++r) {
            const int i_loc = lg * 4 + r;
            float s0 = sv[0][r] * 0.125f, s1 = sv[1][r] * 0.125f;
            float s2 = sv[2][r] * 0.125f, s3 = sv[3][r] * 0.125f;
            float pm = fmaxf(fmaxf(s0, s1), fmaxf(s2, s3));
            pm = fmaxf(pm, __shfl_xor(pm, 1, 64));
            pm = fmaxf(pm, __shfl_xor(pm, 2, 64));
            pm = fmaxf(pm, __shfl_xor(pm, 4, 64));
            pm = fmaxf(pm, __shfl_xor(pm, 8, 64));
            const float mnew = fmaxf(m_run[r], pm);
            const float alpha = __expf(m_run[r] - mnew);
            const float p0 = __expf(s0 - mnew), p1 = __expf(s1 - mnew);
            const float p2 = __expf(s2 - mnew), p3 = __expf(s3 - mnew);
            Pl[w][i_loc][0 * 16 + ll] = f2bf(p0);
            Pl[w][i_loc][1 * 16 + ll] = f2bf(p1);
            Pl[w][i_loc][2 * 16 + ll] = f2bf(p2);
            Pl[w][i_loc][3 * 16 + ll] = f2bf(p3);
            float ps = p0 + p1 + p2 + p3;
            ps += __shfl_xor(ps, 1, 64);
            ps += __shfl_xor(ps, 2, 64);
            ps += __shfl_xor(ps, 4, 64);
            ps += __shfl_xor(ps, 8, 64);
            l_run[r] = l_run[r] * alpha + ps;
            m_run[r] = mnew;
#pragma unroll
            for (int ns = 0; ns < 4; ++ns) o_acc[ns][r] *= alpha;
        }

        // O += P @ V
        __builtin_amdgcn_s_setprio(1);
        const bf16x8 ap0 = *(const bf16x8*)&Pl[w][ll][lg * 8];
        const bf16x8 ap1 = *(const bf16x8*)&Pl[w][ll][32 + lg * 8];
#pragma unroll
        for (int ns = 0; ns < 4; ++ns) {
            const bf16x8 bv0 = *(const bf16x8*)&Vt[buf][ns * 16 + ll][lg * 8];
            const bf16x8 bv1 = *(const bf16x8*)&Vt[buf][ns * 16 + ll][32 + lg * 8];
            o_acc[ns] = mfma16(ap0, bv0, o_acc[ns]);
            o_acc[ns] = mfma16(ap1, bv1, o_acc[ns]);
        }
        __builtin_amdgcn_s_setprio(0);
    }

#pragma unroll
    for (int ns = 0; ns < 4; ++ns)
#pragma unroll
        for (int r = 0; r < 4; ++r) {
            const int row = iw0 + lg * 4 + r;
            outp[(size_t)(b * T + row) * 1024 + h * 64 + ns * 16 + ll] =
                f2bf(o_acc[ns][r] / l_run[r]);
        }
}

// ------------------------------- launch ---------------------------------
extern "C" void kernel_launch(void* const* d_in, const int* in_sizes, int n_in,
                              void* d_out, int out_size, void* d_ws, size_t ws_size,
                              hipStream_t stream) {
    const float* x    = (const float*)d_in[0];
    const float* mem  = (const float*)d_in[1];
    const float* Wq   = (const float*)d_in[2];
    const float* Wk   = (const float*)d_in[3];
    const float* Wv   = (const float*)d_in[4];
    const float* Wr   = (const float*)d_in[5];
    const float* Wo   = (const float*)d_in[6];
    const float* bu   = (const float*)d_in[7];
    const float* bv   = (const float*)d_in[8];
    const float* ln1g = (const float*)d_in[9];
    const float* ln1b = (const float*)d_in[10];
    const float* ln2g = (const float*)d_in[11];
    const float* ln2b = (const float*)d_in[12];
    const float* W1   = (const float*)d_in[13];
    const float* b1   = (const float*)d_in[14];
    const float* W2   = (const float*)d_in[15];
    const float* b2   = (const float*)d_in[16];

    float* y_out   = (float*)d_out;             // [4,1024,1024] fp32, step 9
    float* mem_out = (float*)d_out + 4194304;   // new_mem = x (fp32), step 6.5

    // ===== d_out (32 MB fp32) as scratch, time-multiplexed =====
    // [0,8)MB attno[5,6] -> y[9]; [8,12) pe[1,2];
    // [12,16.32) rbuf_alloc (80-row pads)[2,5]; [16.5,26.5) WqT..WoT [1,6]
    // mem_out bytes [16,32) written step 6.5 (all scratch there dead).
    char* dob = (char*)d_out;
    u16* attno     = (u16*)(dob + 0);
    u16* pe        = (u16*)(dob + (size_t)8  * 1048576);
    u16* rbuf_base = (u16*)(dob + (size_t)12 * 1048576);
    u16* rbuf      = rbuf_base + 80 * 1024;           // padded +/-80 rows
    char* dw = dob + (size_t)16 * 1048576 + 524288;   // 16.5 MB
    u16* WqT = (u16*)(dw);
    u16* WkT = (u16*)(dw + (size_t)2 * 1048576);
    u16* WvT = (u16*)(dw + (size_t)4 * 1048576);
    u16* WrT = (u16*)(dw + (size_t)6 * 1048576);
    u16* WoT = (u16*)(dw + (size_t)8 * 1048576);

    // ===== ws layout, extent 64 MB =====
    char* ws = (char*)d_ws;
    const size_t MB = 1u << 20;
    u16*  xn    = (u16*)(ws + 0 * MB);
    u16*  x2n   = (u16*)(ws + 0 * MB);
    u16*  W2T   = (u16*)(ws + 0 * MB);
    u16*  qu    = (u16*)(ws + 8 * MB);
    float* x2f  = (float*)(ws + 8 * MB);
    u16*  qv    = (u16*)(ws + 16 * MB);
    u16*  kcat  = (u16*)(ws + 24 * MB);
    u16*  ffh   = (u16*)(ws + 24 * MB);
    u16*  vcat  = (u16*)(ws + 40 * MB);
    u16*  memb  = (u16*)(ws + 56 * MB);
    u16*  W1T   = (u16*)(ws + 56 * MB);

    // step 1: weight transposes (fp32 -> bf16 W^T), pe, mem convert, LN1
    transpose_kernel<<<dim3(32, 32), 256, 0, stream>>>(Wq, WqT, 1024, 1024);
    transpose_kernel<<<dim3(32, 32), 256, 0, stream>>>(Wk, WkT, 1024, 1024);
    transpose_kernel<<<dim3(32, 32), 256, 0, stream>>>(Wv, WvT, 1024, 1024);
    transpose_kernel<<<dim3(32, 32), 256, 0, stream>>>(Wr, WrT, 1024, 1024);
    transpose_kernel<<<dim3(32, 32), 256, 0, stream>>>(Wo, WoT, 1024, 1024);
    pe_kernel<<<8192, 256, 0, stream>>>(pe);
    convert_kernel<<<2048, 256, 0, stream>>>(mem, memb);
    ln_kernel<<<1024, 256, 0, stream>>>(x, ln1g, ln1b, xn);
    // step 2: r = pe @ Wr  (writes unpadded rbuf rows [0,2048))
    gemm_kernel<0, false><<<dim3(16, 8), 256, 0, stream>>>(pe, nullptr, WrT, rbuf, nullptr, nullptr, nullptr, nullptr, 2048, 1024, 1024);
    // step 3: qu/qv = xn @ Wq (+bias_u / +bias_v)
    gemm_kernel<1, false><<<dim3(32, 8), 256, 0, stream>>>(xn, nullptr, WqT, qu, qv, bu, bv, nullptr, 4096, 1024, 1024);
    // step 4: k/v = [memb; xn] @ Wk/Wv
    gemm_kernel<0, true><<<dim3(64, 8), 256, 0, stream>>>(memb, xn, WkT, kcat, nullptr, nullptr, nullptr, nullptr, 8192, 1024, 1024);
    gemm_kernel<0, true><<<dim3(64, 8), 256, 0, stream>>>(memb, xn, WvT, vcat, nullptr, nullptr, nullptr, nullptr, 8192, 1024, 1024);
    // step 5: fused attention -> attno
    attn_kernel<<<1024, 256, 0, stream>>>(qu, qv, kcat, vcat, rbuf, attno);
    // step 6: x2 = x + attn @ Wo (fp32; x2f overlays dead qu/qv)
    gemm_kernel<2, false><<<dim3(32, 8), 256, 0, stream>>>(attno, nullptr, WoT, x2f, nullptr, nullptr, nullptr, x, 4096, 1024, 1024);
    // step 6.5: W1T into memb slot (memb dead); new_mem = x (fp32 copy)
    transpose_kernel<<<dim3(128, 32), 256, 0, stream>>>(W1, W1T, 1024, 4096);
    hipMemcpyAsync(mem_out, x, (size_t)4194304 * 4, hipMemcpyDeviceToDevice, stream);
    // step 7: LN2 (x2n overlays xn; xn dead)
    ln_kernel<<<1024, 256, 0, stream>>>(x2f, ln2g, ln2b, x2n);
    // step 8: ffh = gelu(x2n @ W1 + b1)  (ffh overlays dead kcat/vcat)
    gemm_kernel<3, false><<<dim3(32, 32), 256, 0, stream>>>(x2n, nullptr, W1T, ffh, nullptr, b1, nullptr, nullptr, 4096, 4096, 1024);
    // step 8.5: W2T into x2n slot (x2n dead after step 8)
    transpose_kernel<<<dim3(32, 128), 256, 0, stream>>>(W2, W2T, 4096, 1024);
    // step 9: y = x2 + ffh @ W2 + b2 (fp32 out; clobbers attno/pe/rbuf, dead)
    gemm_kernel<4, false><<<dim3(32, 8), 256, 0, stream>>>(ffh, nullptr, W2T, y_out, nullptr, b2, nullptr, x2f, 4096, 1024, 4096);
    (void)in_sizes; (void)n_in; (void)out_size; (void)ws_size;
}

// Round 12
// 599.767 us; speedup vs baseline: 1.4053x; 1.4053x over previous
//
#include <hip/hip_runtime.h>
#include <hip/hip_bf16.h>

typedef short bf16x8 __attribute__((ext_vector_type(8)));
typedef float f32x4 __attribute__((ext_vector_type(4)));
typedef unsigned short u16;

__device__ __forceinline__ float bf2f(u16 u) {
    union { unsigned int i; float f; } x; x.i = ((unsigned int)u) << 16; return x.f;
}
__device__ __forceinline__ u16 f2bf(float f) {
    union { float f; unsigned int i; } x; x.f = f;
    unsigned int r = x.i + 0x7fff + ((x.i >> 16) & 1);
    return (u16)(r >> 16);
}
__device__ __forceinline__ f32x4 mfma16(bf16x8 a, bf16x8 b, f32x4 c) {
    return __builtin_amdgcn_mfma_f32_16x16x32_bf16(a, b, c, 0, 0, 0);
}
#define GLL16(lds_base, gsrc) \
    __builtin_amdgcn_global_load_lds((const __attribute__((address_space(1))) void*)(gsrc), \
                                     (__attribute__((address_space(3))) void*)(lds_base), 16, 0, 0)

// ------------- transpose fp32 [R][C] -> bf16 [C][R] ---------------------
__global__ __launch_bounds__(256)
void transpose_kernel(const float* __restrict__ in, u16* __restrict__ out, int R, int C) {
    __shared__ float t[32][33];
    const int c0 = blockIdx.x * 32, r0 = blockIdx.y * 32;
    const int tx = threadIdx.x & 31, ty = threadIdx.x >> 5; // ty 0..7
#pragma unroll
    for (int i = 0; i < 32; i += 8) t[ty + i][tx] = in[(size_t)(r0 + ty + i) * C + c0 + tx];
    __syncthreads();
#pragma unroll
    for (int i = 0; i < 32; i += 8) out[(size_t)(c0 + ty + i) * R + r0 + tx] = f2bf(t[tx][ty + i]);
}

// ------------- fp32 -> bf16 convert (8 elems/thread) --------------------
__global__ __launch_bounds__(256)
void convert_kernel(const float* __restrict__ in, u16* __restrict__ out) {
    const size_t i = ((size_t)blockIdx.x * 256 + threadIdx.x) * 8;
    const float4 a = *(const float4*)(in + i);
    const float4 b = *(const float4*)(in + i + 4);
    bf16x8 o;
    o[0] = (short)f2bf(a.x); o[1] = (short)f2bf(a.y);
    o[2] = (short)f2bf(a.z); o[3] = (short)f2bf(a.w);
    o[4] = (short)f2bf(b.x); o[5] = (short)f2bf(b.y);
    o[6] = (short)f2bf(b.z); o[7] = (short)f2bf(b.w);
    *(bf16x8*)(out + i) = o;
}

// ------------- positional embedding pe[2048][1024] (bf16) ---------------
__global__ __launch_bounds__(256)
void pe_kernel(u16* __restrict__ pe) {
    const int idx = blockIdx.x * 256 + threadIdx.x; // 2M elements
    const int p = idx >> 10, d = idx & 1023;
    const float pos = (float)(2047 - p);
    const int k = d & 511;
    const float invf = powf(10000.f, ((float)(2 * k)) * (-1.f / 1024.f));
    const float a = pos * invf;
    pe[idx] = f2bf((d < 512) ? sinf(a) : cosf(a));
}

// ------------- LayerNorm (fp32 in, bf16 out), one wave per row ----------
__global__ __launch_bounds__(256)
void ln_kernel(const float* __restrict__ inp, const float* __restrict__ gg,
               const float* __restrict__ bb, u16* __restrict__ outp) {
    const int row = blockIdx.x * 4 + (threadIdx.x >> 6);
    const int l = threadIdx.x & 63;
    const size_t base = (size_t)row * 1024 + l * 16;
    float v[16];
    const float4* p4 = (const float4*)(inp + base);
#pragma unroll
    for (int j = 0; j < 4; ++j) {
        float4 f = p4[j];
        v[j*4+0] = f.x; v[j*4+1] = f.y; v[j*4+2] = f.z; v[j*4+3] = f.w;
    }
    float s = 0.f, s2 = 0.f;
#pragma unroll
    for (int j = 0; j < 16; ++j) { s += v[j]; s2 += v[j] * v[j]; }
#pragma unroll
    for (int off = 1; off < 64; off <<= 1) {
        s += __shfl_xor(s, off, 64);
        s2 += __shfl_xor(s2, off, 64);
    }
    const float mu = s * 0.0009765625f;
    const float var = s2 * 0.0009765625f - mu * mu;
    const float rs = rsqrtf(var + 1e-5f);
#pragma unroll
    for (int j = 0; j < 16; ++j)
        outp[base + j] = f2bf((v[j] - mu) * rs * gg[l * 16 + j] + bb[l * 16 + j]);
}

// ---------------- GEMM: C[M][N] = A[M][K] @ W[K][N], Wt = W^T [N][K] ----
template<int EPI, bool CATA>
__global__ __launch_bounds__(256)
void gemm_kernel(const u16* __restrict__ A, const u16* __restrict__ A2,
                 const u16* __restrict__ Wt, void* __restrict__ outp,
                 u16* __restrict__ out2, const float* __restrict__ cb1,
                 const float* __restrict__ cb2, const float* __restrict__ residp,
                 int Mdim, int Ndim, int Kdim) {
    __shared__ __attribute__((aligned(16))) u16 As[128 * 32];
    __shared__ __attribute__((aligned(16))) u16 Bs[128 * 32];
    const int tid = threadIdx.x;
    const int w = tid >> 6, l = tid & 63;
    const int wr = w >> 1, wc = w & 1;
    const int m0 = blockIdx.x * 128, n0 = blockIdx.y * 128;
    f32x4 acc[4][4] = {};

    for (int k0 = 0; k0 < Kdim; k0 += 32) {
        __syncthreads();
#pragma unroll
        for (int p = 0; p < 2; ++p) {
            const int ebase = (p * 4 + w) * 512;
            const int e = ebase + l * 8;
            const int row = e >> 5, colk = e & 31;
            const u16* srcA;
            if (CATA) {
                const int rr = m0 + row;
                const int bb_ = rr >> 11, pos = rr & 2047;
                srcA = (pos < 1024 ? A + ((size_t)(bb_ * 1024 + pos)) * 1024
                                   : A2 + ((size_t)(bb_ * 1024 + pos - 1024)) * 1024)
                       + (k0 + colk);
            } else {
                srcA = A + (size_t)(m0 + row) * Kdim + (k0 + colk);
            }
            const u16* srcB = Wt + (size_t)(n0 + row) * Kdim + (k0 + colk);
            GLL16(&As[ebase], srcA);
            GLL16(&Bs[ebase], srcB);
        }
        __syncthreads();
        bf16x8 af[4], bfr[4];
#pragma unroll
        for (int mi = 0; mi < 4; ++mi)
            af[mi] = *(const bf16x8*)&As[(wr * 64 + mi * 16 + (l & 15)) * 32 + (l >> 4) * 8];
#pragma unroll
        for (int ni = 0; ni < 4; ++ni)
            bfr[ni] = *(const bf16x8*)&Bs[(wc * 64 + ni * 16 + (l & 15)) * 32 + (l >> 4) * 8];
#pragma unroll
        for (int mi = 0; mi < 4; ++mi)
#pragma unroll
            for (int ni = 0; ni < 4; ++ni)
                acc[mi][ni] = mfma16(af[mi], bfr[ni], acc[mi][ni]);
    }

#pragma unroll
    for (int mi = 0; mi < 4; ++mi)
#pragma unroll
        for (int ni = 0; ni < 4; ++ni)
#pragma unroll
            for (int rg = 0; rg < 4; ++rg) {
                const int row = m0 + wr * 64 + mi * 16 + (l >> 4) * 4 + rg;
                const int col = n0 + wc * 64 + ni * 16 + (l & 15);
                const size_t idx = (size_t)row * Ndim + col;
                const float v = acc[mi][ni][rg];
                if (EPI == 0) {
                    ((u16*)outp)[idx] = f2bf(v);
                } else if (EPI == 1) {
                    ((u16*)outp)[idx] = f2bf(v + cb1[col]);
                    out2[idx] = f2bf(v + cb2[col]);
                } else if (EPI == 2) {
                    ((float*)outp)[idx] = v + residp[idx];
                } else if (EPI == 3) {
                    const float t = v + cb1[col];
                    ((u16*)outp)[idx] = f2bf(0.5f * t * (1.f + erff(t * 0.70710678118654752f)));
                } else {
                    ((float*)outp)[idx] = v + cb1[col] + residp[idx]; // fp32 y
                }
            }
}

// ---------------- fused rel-attention: LDS-staged K and R bands ---------
// grid: 1024 blocks (XCD-swizzled), 256 threads (4 waves x 16 q-rows).
// K tile + both 128-row R-band tiles staged per jt via global_load_lds
// (linear dest + pre-swizzled source cols; XOR-swizzled ds_read_b128).
__global__ __launch_bounds__(256, 2)
void attn_kernel(const u16* __restrict__ qu, const u16* __restrict__ qv,
                 const u16* __restrict__ kcat, const u16* __restrict__ vcat,
                 const u16* __restrict__ rbuf, u16* __restrict__ outp) {
    constexpr int T = 1024, L = 2048, MM = 1024;
    __shared__ __attribute__((aligned(16))) u16 KtL[64 * 64];   // 8KB swizzled
    __shared__ __attribute__((aligned(16))) u16 RmL[128 * 64];  // 16KB swizzled
    __shared__ __attribute__((aligned(16))) u16 RwL[128 * 64];  // 16KB swizzled
    __shared__ __attribute__((aligned(16))) u16 Vt[64][72];     // 9KB
    __shared__ __attribute__((aligned(16))) u16 Pl[4][16][72];  // 9KB
    const int bid = blockIdx.x;
    const int g = (bid & 7) + 8 * (bid >> 7);   // head-group (XCD swizzle)
    const int it = (bid >> 3) & 15;
    const int h = g & 15, b = g >> 4;
    const int i0 = it * 64;
    const int tid = threadIdx.x;
    const int w = tid >> 6, l = tid & 63;
    const int lg = l >> 4, ll = l & 15;
    const int iw0 = i0 + w * 16;
    const int l8 = l >> 3;                        // stage: row-in-8 group
    const int ssrc = ((l & 7) * 8) ^ (l8 << 3);   // pre-swizzled source col (u16)
    const int sA = (lg * 8) ^ ((ll & 7) << 3);        // frag read col lo (u16)
    const int sB = (lg * 8 + 32) ^ ((ll & 7) << 3);   // frag read col hi (u16)

    bf16x8 quf[2], qvf[2];
    const int qc = h * 64 + lg * 8;
    {
        const size_t qrow = (size_t)(b * T + iw0 + ll);
        quf[0] = *(const bf16x8*)&qu[qrow * 1024 + qc];
        quf[1] = *(const bf16x8*)&qu[qrow * 1024 + qc + 32];
        qvf[0] = *(const bf16x8*)&qv[qrow * 1024 + qc];
        qvf[1] = *(const bf16x8*)&qv[qrow * 1024 + qc + 32];
    }
    const int r2 = iw0 + ll + 1;
    const size_t qrow2 = (size_t)(b * T + (r2 < T ? r2 : T - 1)); // wrap row (lazy)
    const u16* kb = kcat + (size_t)b * L * 1024 + h * 64;
    const u16* vb = vcat + (size_t)b * L * 1024 + h * 64;
    const u16* rb = rbuf + h * 64;

    f32x4 o_acc[4] = {};
    float m_run[4] = {-1e30f, -1e30f, -1e30f, -1e30f};
    float l_run[4] = {0.f, 0.f, 0.f, 0.f};
    const int vjq = tid & 15, vdg = tid >> 4;

    for (int jt = 0; jt < 32; ++jt) {
        const int j0 = jt * 64;
        const bool main_blk = (j0 <= MM + i0 + 63);
        const bool wrap_blk = (j0 + 63 >= MM + i0 + 2);
        __syncthreads();   // all waves done with previous tiles
        // ---- stage K (8 calls), R bands (16 each), V (reg transpose) ----
#pragma unroll
        for (int p = 0; p < 2; ++p) {
            const int k8 = w * 2 + p;
            GLL16(&KtL[k8 * 512], kb + (size_t)(j0 + k8 * 8 + l8) * 1024 + ssrc);
        }
        if (main_blk) {
            const long bm = (long)j0 + T - i0 - 64;  // rows [bm, bm+128) (pad ok)
#pragma unroll
            for (int p = 0; p < 4; ++p) {
                const int k8 = w * 4 + p;
                GLL16(&RmL[k8 * 512], rb + (long)(bm + k8 * 8 + l8) * 1024 + ssrc);
            }
        }
        if (wrap_blk) {
            const long bw_ = (long)j0 - MM - i0 - 65; // can be negative (pad ok)
#pragma unroll
            for (int p = 0; p < 4; ++p) {
                const int k8 = w * 4 + p;
                GLL16(&RwL[k8 * 512], rb + (long)(bw_ + k8 * 8 + l8) * 1024 + ssrc);
            }
        }
        { // V^T stage: reg 4x4 transpose
            const u16* srcv = vb + (size_t)(j0 + vjq * 4) * 1024 + vdg * 4;
            const ushort4 r0 = *(const ushort4*)(srcv);
            const ushort4 r1 = *(const ushort4*)(srcv + 1024);
            const ushort4 r2w = *(const ushort4*)(srcv + 2048);
            const ushort4 r3 = *(const ushort4*)(srcv + 3072);
            const ushort4 c0 = {r0.x, r1.x, r2w.x, r3.x};
            const ushort4 c1 = {r0.y, r1.y, r2w.y, r3.y};
            const ushort4 c2 = {r0.z, r1.z, r2w.z, r3.z};
            const ushort4 c3 = {r0.w, r1.w, r2w.w, r3.w};
            *(ushort4*)&Vt[vdg * 4 + 0][vjq * 4] = c0;
            *(ushort4*)&Vt[vdg * 4 + 1][vjq * 4] = c1;
            *(ushort4*)&Vt[vdg * 4 + 2][vjq * 4] = c2;
            *(ushort4*)&Vt[vdg * 4 + 3][vjq * 4] = c3;
        }
        __syncthreads();   // staged data visible

        // ---- content scores from KtL ----
        f32x4 sv[4];
        __builtin_amdgcn_s_setprio(1);
#pragma unroll
        for (int ns = 0; ns < 4; ++ns) {
            const int rowb = (ns * 16 + ll) * 64;
            f32x4 a = {0.f, 0.f, 0.f, 0.f};
            a = mfma16(quf[0], *(const bf16x8*)&KtL[rowb + sA], a);
            a = mfma16(quf[1], *(const bf16x8*)&KtL[rowb + sB], a);
            sv[ns] = a;
        }
        __builtin_amdgcn_s_setprio(0);

        // ---- main band from RmL (wave tile-row base 48-16w) ----
        if (j0 <= MM + iw0 + 15) {
            const int trb = 48 - 16 * w;
            f32x4 gb[5];
#pragma unroll
            for (int cs = 0; cs < 5; ++cs) {
                const int rowb = (trb + cs * 16 + ll) * 64;
                f32x4 a = {0.f, 0.f, 0.f, 0.f};
                a = mfma16(qvf[0], *(const bf16x8*)&RmL[rowb + sA], a);
                a = mfma16(qvf[1], *(const bf16x8*)&RmL[rowb + sB], a);
                gb[cs] = a;
            }
#pragma unroll
            for (int r = 0; r < 4; ++r) {
                const int i_loc = lg * 4 + r;
                const int ig = iw0 + i_loc;
#pragma unroll
                for (int ns = 0; ns < 4; ++ns) {
                    const int j_loc = ns * 16 + ll;
                    const int c = j_loc + 15 - i_loc;
                    const int srcl = (l & 48) | (c & 15);
                    const float t0 = __shfl(gb[ns][r], srcl, 64);
                    const float t1 = __shfl(gb[ns + 1][r], srcl, 64);
                    const float gm = ((c >> 4) == ns) ? t0 : t1;
                    if (j0 + j_loc <= MM + ig) sv[ns][r] += gm;
                }
            }
        }
        // ---- wrap band from RwL ----
        if (j0 + 63 >= MM + iw0 + 2) {
            const bf16x8 qv2f0 = *(const bf16x8*)&qv[qrow2 * 1024 + qc];
            const bf16x8 qv2f1 = *(const bf16x8*)&qv[qrow2 * 1024 + qc + 32];
            const int trb = 48 - 16 * w;
            f32x4 gb[5];
#pragma unroll
            for (int cs = 0; cs < 5; ++cs) {
                const int rowb = (trb + cs * 16 + ll) * 64;
                f32x4 a = {0.f, 0.f, 0.f, 0.f};
                a = mfma16(qv2f0, *(const bf16x8*)&RwL[rowb + sA], a);
                a = mfma16(qv2f1, *(const bf16x8*)&RwL[rowb + sB], a);
                gb[cs] = a;
            }
#pragma unroll
            for (int r = 0; r < 4; ++r) {
                const int i_loc = lg * 4 + r;
                const int ig = iw0 + i_loc;
#pragma unroll
                for (int ns = 0; ns < 4; ++ns) {
                    const int j_loc = ns * 16 + ll;
                    const int c = j_loc + 15 - i_loc;
                    const int srcl = (l & 48) | (c & 15);
                    const float t0 = __shfl(gb[ns][r], srcl, 64);
                    const float t1 = __shfl(gb[ns + 1][r], srcl, 64);
                    const float gw = ((c >> 4) == ns) ? t0 : t1;
                    if (j0 + j_loc >= MM + ig + 2) sv[ns][r] += gw;
                }
            }
        }

        // ---- online softmax + write P ----
#pragma unroll
        for (int r = 0; r < 4; ++r) {
            const int i_loc = lg * 4 + r;
            float s0 = sv[0][r] * 0.125f, s1 = sv[1][r] * 0.125f;
            float s2 = sv[2][r] * 0.125f, s3 = sv[3][r] * 0.125f;
            float pm = fmaxf(fmaxf(s0, s1), fmaxf(s2, s3));
            pm = fmaxf(pm, __shfl_xor(pm, 1, 64));
            pm = fmaxf(pm, __shfl_xor(pm, 2, 64));
            pm = fmaxf(pm, __shfl_xor(pm, 4, 64));
            pm = fmaxf(pm, __shfl_xor(pm, 8, 64));
            const float mnew = fmaxf(m_run[r], pm);
            const float alpha = __expf(m_run[r] - mnew);
            const float p0 = __expf(s0 - mnew), p1 = __expf(s1 - mnew);
            const float p2 = __expf(s2 - mnew), p3 = __expf(s3 - mnew);
            Pl[w][i_loc][0 * 16 + ll] = f2bf(p0);
            Pl[w][i_loc][1 * 16 + ll] = f2bf(p1);
            Pl[w][i_loc][2 * 16 + ll] = f2bf(p2);
            Pl[w][i_loc][3 * 16 + ll] = f2bf(p3);
            float ps = p0 + p1 + p2 + p3;
            ps += __shfl_xor(ps, 1, 64);
            ps += __shfl_xor(ps, 2, 64);
            ps += __shfl_xor(ps, 4, 64);
            ps += __shfl_xor(ps, 8, 64);
            l_run[r] = l_run[r] * alpha + ps;
            m_run[r] = mnew;
#pragma unroll
            for (int ns = 0; ns < 4; ++ns) o_acc[ns][r] *= alpha;
        }

        // ---- O += P @ V ----
        __builtin_amdgcn_s_setprio(1);
        const bf16x8 ap0 = *(const bf16x8*)&Pl[w][ll][lg * 8];
        const bf16x8 ap1 = *(const bf16x8*)&Pl[w][ll][32 + lg * 8];
#pragma unroll
        for (int ns = 0; ns < 4; ++ns) {
            const bf16x8 bv0 = *(const bf16x8*)&Vt[ns * 16 + ll][lg * 8];
            const bf16x8 bv1 = *(const bf16x8*)&Vt[ns * 16 + ll][32 + lg * 8];
            o_acc[ns] = mfma16(ap0, bv0, o_acc[ns]);
            o_acc[ns] = mfma16(ap1, bv1, o_acc[ns]);
        }
        __builtin_amdgcn_s_setprio(0);
    }

#pragma unroll
    for (int ns = 0; ns < 4; ++ns)
#pragma unroll
        for (int r = 0; r < 4; ++r) {
            const int row = iw0 + lg * 4 + r;
            outp[(size_t)(b * T + row) * 1024 + h * 64 + ns * 16 + ll] =
                f2bf(o_acc[ns][r] / l_run[r]);
        }
}

// ------------------------------- launch ---------------------------------
extern "C" void kernel_launch(void* const* d_in, const int* in_sizes, int n_in,
                              void* d_out, int out_size, void* d_ws, size_t ws_size,
                              hipStream_t stream) {
    const float* x    = (const float*)d_in[0];
    const float* mem  = (const float*)d_in[1];
    const float* Wq   = (const float*)d_in[2];
    const float* Wk   = (const float*)d_in[3];
    const float* Wv   = (const float*)d_in[4];
    const float* Wr   = (const float*)d_in[5];
    const float* Wo   = (const float*)d_in[6];
    const float* bu   = (const float*)d_in[7];
    const float* bv   = (const float*)d_in[8];
    const float* ln1g = (const float*)d_in[9];
    const float* ln1b = (const float*)d_in[10];
    const float* ln2g = (const float*)d_in[11];
    const float* ln2b = (const float*)d_in[12];
    const float* W1   = (const float*)d_in[13];
    const float* b1   = (const float*)d_in[14];
    const float* W2   = (const float*)d_in[15];
    const float* b2   = (const float*)d_in[16];

    float* y_out   = (float*)d_out;
    float* mem_out = (float*)d_out + 4194304;

    // ===== d_out (32 MB fp32) as scratch, time-multiplexed =====
    char* dob = (char*)d_out;
    u16* attno     = (u16*)(dob + 0);
    u16* pe        = (u16*)(dob + (size_t)8  * 1048576);
    u16* rbuf_base = (u16*)(dob + (size_t)12 * 1048576);
    u16* rbuf      = rbuf_base + 80 * 1024;           // padded +/-80 rows
    char* dw = dob + (size_t)16 * 1048576 + 524288;   // 16.5 MB
    u16* WqT = (u16*)(dw);
    u16* WkT = (u16*)(dw + (size_t)2 * 1048576);
    u16* WvT = (u16*)(dw + (size_t)4 * 1048576);
    u16* WrT = (u16*)(dw + (size_t)6 * 1048576);
    u16* WoT = (u16*)(dw + (size_t)8 * 1048576);

    // ===== ws layout, extent 64 MB =====
    char* ws = (char*)d_ws;
    const size_t MB = 1u << 20;
    u16*  xn    = (u16*)(ws + 0 * MB);
    u16*  x2n   = (u16*)(ws + 0 * MB);
    u16*  W2T   = (u16*)(ws + 0 * MB);
    u16*  qu    = (u16*)(ws + 8 * MB);
    float* x2f  = (float*)(ws + 8 * MB);
    u16*  qv    = (u16*)(ws + 16 * MB);
    u16*  kcat  = (u16*)(ws + 24 * MB);
    u16*  ffh   = (u16*)(ws + 24 * MB);
    u16*  vcat  = (u16*)(ws + 40 * MB);
    u16*  memb  = (u16*)(ws + 56 * MB);
    u16*  W1T   = (u16*)(ws + 56 * MB);

    transpose_kernel<<<dim3(32, 32), 256, 0, stream>>>(Wq, WqT, 1024, 1024);
    transpose_kernel<<<dim3(32, 32), 256, 0, stream>>>(Wk, WkT, 1024, 1024);
    transpose_kernel<<<dim3(32, 32), 256, 0, stream>>>(Wv, WvT, 1024, 1024);
    transpose_kernel<<<dim3(32, 32), 256, 0, stream>>>(Wr, WrT, 1024, 1024);
    transpose_kernel<<<dim3(32, 32), 256, 0, stream>>>(Wo, WoT, 1024, 1024);
    pe_kernel<<<8192, 256, 0, stream>>>(pe);
    convert_kernel<<<2048, 256, 0, stream>>>(mem, memb);
    ln_kernel<<<1024, 256, 0, stream>>>(x, ln1g, ln1b, xn);
    gemm_kernel<0, false><<<dim3(16, 8), 256, 0, stream>>>(pe, nullptr, WrT, rbuf, nullptr, nullptr, nullptr, nullptr, 2048, 1024, 1024);
    gemm_kernel<1, false><<<dim3(32, 8), 256, 0, stream>>>(xn, nullptr, WqT, qu, qv, bu, bv, nullptr, 4096, 1024, 1024);
    gemm_kernel<0, true><<<dim3(64, 8), 256, 0, stream>>>(memb, xn, WkT, kcat, nullptr, nullptr, nullptr, nullptr, 8192, 1024, 1024);
    gemm_kernel<0, true><<<dim3(64, 8), 256, 0, stream>>>(memb, xn, WvT, vcat, nullptr, nullptr, nullptr, nullptr, 8192, 1024, 1024);
    attn_kernel<<<1024, 256, 0, stream>>>(qu, qv, kcat, vcat, rbuf, attno);
    gemm_kernel<2, false><<<dim3(32, 8), 256, 0, stream>>>(attno, nullptr, WoT, x2f, nullptr, nullptr, nullptr, x, 4096, 1024, 1024);
    transpose_kernel<<<dim3(128, 32), 256, 0, stream>>>(W1, W1T, 1024, 4096);
    hipMemcpyAsync(mem_out, x, (size_t)4194304 * 4, hipMemcpyDeviceToDevice, stream);
    ln_kernel<<<1024, 256, 0, stream>>>(x2f, ln2g, ln2b, x2n);
    gemm_kernel<3, false><<<dim3(32, 32), 256, 0, stream>>>(x2n, nullptr, W1T, ffh, nullptr, b1, nullptr, nullptr, 4096, 4096, 1024);
    transpose_kernel<<<dim3(32, 128), 256, 0, stream>>>(W2, W2T, 4096, 1024);
    gemm_kernel<4, false><<<dim3(32, 8), 256, 0, stream>>>(ffh, nullptr, W2T, y_out, nullptr, b2, nullptr, x2f, 4096, 1024, 4096);
    (void)in_sizes; (void)n_in; (void)out_size; (void)ws_size;
}